// Round 7
// baseline (127.000 us; speedup 1.0000x reference)
//
#include <hip/hip_runtime.h>
#include <hip/hip_bf16.h>

#define B_ 8
#define S_ 2048
#define F_ 1024
#define DK_ 128
#define M_ (B_*S_)          // 16384

typedef unsigned short u16;
typedef short short8 __attribute__((ext_vector_type(8)));
typedef float f32x4 __attribute__((ext_vector_type(4)));
typedef float f32x16 __attribute__((ext_vector_type(16)));

__device__ __forceinline__ u16 f2bf(float f) {
    unsigned int u = __float_as_uint(f);
    u += 0x7FFFu + ((u >> 16) & 1u);    // round-to-nearest-even
    return (u16)(u >> 16);
}
__device__ __forceinline__ float fexp2(float x) {
#if __has_builtin(__builtin_amdgcn_exp2f)
    return __builtin_amdgcn_exp2f(x);   // raw v_exp_f32 (2^x)
#else
    return exp2f(x);
#endif
}
__device__ __forceinline__ unsigned int cvt_pk_bf16(float lo, float hi) {
    unsigned int r;
    asm volatile("v_cvt_pk_bf16_f32 %0, %1, %2" : "=v"(r) : "v"(lo), "v"(hi));
    return r;
}

// ---------------------------------------------------------------------------
// Kernel 1: W [1024][128] fp32 -> WT [3][128][1024] bf16 (transposed).
// w_q gets (1/sqrt(128)) * log2(e) folded in, so softmax uses raw exp2.
// ---------------------------------------------------------------------------
__global__ __launch_bounds__(256) void prep_wt(const float* __restrict__ wq,
                                               const float* __restrict__ wk,
                                               const float* __restrict__ wv,
                                               u16* __restrict__ WT) {
    int id = blockIdx.x * 256 + threadIdx.x;
    if (id >= 3 * DK_ * F_) return;
    int m   = id / (DK_ * F_);
    int rem = id - m * (DK_ * F_);
    int c   = rem / F_;
    int k   = rem - c * F_;
    const float* w = (m == 0) ? wq : (m == 1) ? wk : wv;
    float v = w[k * DK_ + c];
    if (m == 0) v *= 0.12751741951f;   // (1/sqrt(128)) * log2(e)
    WT[id] = f2bf(v);
}

// ---------------------------------------------------------------------------
// Kernel 2: projection GEMM, restructured for barrier amortization.
// X [16384][1024] fp32 (streamed direct from global as A-fragments, with
// inline fp32->bf16 cvt_pk; zero reuse so no LDS for X). W staged in LDS in
// K-chunks of 128 (34 KB padded [128][136], 2 barriers per 32 MFMAs; the old
// BK=32 version paid 2 barriers per 8 MFMAs = 64 drains/block).
// mode 0: qp [16384][128], mode 1: kp [16384][128], mode 2: vpT [128][16384]
// Block 256 thr (4 waves), tile 64 rows x 128 cols (16 rows/wave).
// ---------------------------------------------------------------------------
__global__ __launch_bounds__(256, 4) void proj(const float* __restrict__ xq,
                                               const float* __restrict__ xk,
                                               const float* __restrict__ xv,
                                               const u16* __restrict__ WT,
                                               u16* __restrict__ qp,
                                               u16* __restrict__ kp,
                                               u16* __restrict__ vpT) {
    const int mode = blockIdx.y;
    const float* X = (mode == 0) ? xq : (mode == 1) ? xk : xv;
    const u16*   W = WT + mode * (DK_ * F_);

    // row stride 136 u16 = 272 B = 68 dwords; 68 mod 32 = 4 -> rows 0..7 hit
    // distinct bank groups, 16 rows = 2-way (free). 34 KB.
    __shared__ u16 w_lds[128][136];

    const int t    = threadIdx.x;
    const int lane = t & 63;
    const int wv_  = t >> 6;
    const int l15  = lane & 15, l4 = lane >> 4;
    const int row0 = blockIdx.x * 64 + wv_ * 16;   // this wave's 16 rows

    f32x4 acc[8];
#pragma unroll
    for (int j = 0; j < 8; ++j) acc[j] = f32x4{0.f, 0.f, 0.f, 0.f};

    const int sc_ = t >> 1;            // staging row 0..127
    const int sko = (t & 1) * 64;      // staging k-offset (64 u16 = 128 B)

    for (int k0 = 0; k0 < F_; k0 += 128) {
        // ---- stage W chunk [128 c][128 k] (bf16, vector copy)
        {
            const int4* src = (const int4*)(W + (size_t)sc_ * F_ + k0 + sko);
#pragma unroll
            for (int j = 0; j < 8; ++j)
                *(int4*)&w_lds[sc_][sko + j * 8] = src[j];
        }
        __syncthreads();

#pragma unroll
        for (int kc = 0; kc < 4; ++kc) {
            // ---- A-frag: X[row0+l15][k0 + kc*32 + l4*8 .. +7], fp32 -> bf16
            const float4* ax = (const float4*)(X + (size_t)(row0 + l15) * F_
                                                 + k0 + kc * 32 + l4 * 8);
            float4 f0 = ax[0], f1 = ax[1];
            int4 aw;
            aw.x = (int)cvt_pk_bf16(f0.x, f0.y);
            aw.y = (int)cvt_pk_bf16(f0.z, f0.w);
            aw.z = (int)cvt_pk_bf16(f1.x, f1.y);
            aw.w = (int)cvt_pk_bf16(f1.z, f1.w);
            short8 af = *(short8*)&aw;

            if (mode < 2) {
#pragma unroll
                for (int ct = 0; ct < 8; ++ct) {
                    short8 bf = *(const short8*)&w_lds[ct * 16 + l15][kc * 32 + l4 * 8];
                    acc[ct] = __builtin_amdgcn_mfma_f32_16x16x32_bf16(af, bf, acc[ct], 0, 0, 0);
                }
            } else {
#pragma unroll
                for (int ct = 0; ct < 8; ++ct) {
                    short8 bf = *(const short8*)&w_lds[ct * 16 + l15][kc * 32 + l4 * 8];
                    acc[ct] = __builtin_amdgcn_mfma_f32_16x16x32_bf16(bf, af, acc[ct], 0, 0, 0);
                }
            }
        }
        __syncthreads();
    }

    if (mode < 2) {
        u16* OUT = (mode == 0) ? qp : kp;
#pragma unroll
        for (int ct = 0; ct < 8; ++ct)
#pragma unroll
            for (int r = 0; r < 4; ++r) {
                int row = row0 + l4 * 4 + r;
                int col = ct * 16 + l15;
                OUT[(size_t)row * DK_ + col] = f2bf(acc[ct][r]);
            }
    } else {
        // swapped operands: D[row=n][col=m] -> store transposed vpT[n][m]
#pragma unroll
        for (int ct = 0; ct < 8; ++ct)
#pragma unroll
            for (int r = 0; r < 4; ++r) {
                int n = ct * 16 + l4 * 4 + r;
                int m = row0 + l15;
                vpT[(size_t)n * M_ + m] = f2bf(acc[ct][r]);
            }
    }
}

// ---------------------------------------------------------------------------
// Kernel 3: flash attention, swapped-operand 32x32x16 MFMA structure.
// (unchanged from round 6 — attn dropped out of the top-5 with this)
// ---------------------------------------------------------------------------
__global__ __launch_bounds__(512, 2) void attn(const u16* __restrict__ qp,
                                               const u16* __restrict__ kp,
                                               const u16* __restrict__ vpT,
                                               float* __restrict__ out) {
    __shared__ float oA[128 * 33], oB[128 * 33];
    __shared__ float m_lds[8][32], l_lds[8][32], gm_lds[32], gl_lds[32];

    const int t    = threadIdx.x;
    const int lane = t & 63;
    const int wv_  = t >> 6;                 // 0..7
    const int r31  = lane & 31;              // q index (as B-col) / kv,d row (as A-row)
    const int hi   = lane >> 5;              // which 8-wide k-group this lane feeds

    const int b  = blockIdx.x & 7;
    const int qi = blockIdx.x >> 3;
    const int qbase = b * S_ + qi * 32;

    // Q as persistent B-fragments: qf[c] = Q[q=r31][d = c*16 + hi*8 + 0..7]
    short8 qf[8];
#pragma unroll
    for (int c = 0; c < 8; ++c)
        qf[c] = *(const short8*)(qp + (size_t)(qbase + r31) * DK_ + c * 16 + hi * 8);

    f32x16 o4[4];
#pragma unroll
    for (int ct = 0; ct < 4; ++ct)
#pragma unroll
        for (int i = 0; i < 16; ++i) o4[ct][i] = 0.f;
    float mrun = -1.0e30f, lrun = 0.f;

    const int kv_lo = b * S_ + wv_ * 256;

    for (int kt = 0; kt < 8; ++kt) {
        const int kv0 = kv_lo + kt * 32;

        // ---- load K tile (A-frags: row=kv=r31, k=d) and V^T tile (row=d, k=kv)
        short8 kf[8];
#pragma unroll
        for (int c = 0; c < 8; ++c)
            kf[c] = *(const short8*)(kp + (size_t)(kv0 + r31) * DK_ + c * 16 + hi * 8);
        short8 vf[4][2];
#pragma unroll
        for (int ct = 0; ct < 4; ++ct)
#pragma unroll
            for (int ch = 0; ch < 2; ++ch)
                vf[ct][ch] = *(const short8*)(vpT + (size_t)(ct * 32 + r31) * M_
                                                  + kv0 + ch * 16 + hi * 8);

        // ---- QK^T: st[reg] = S^T[kv = (reg&3)+8*(reg>>2)+4*hi][q = r31]
        f32x16 st;
#pragma unroll
        for (int i = 0; i < 16; ++i) st[i] = 0.f;
#pragma unroll
        for (int c = 0; c < 8; ++c)
            st = __builtin_amdgcn_mfma_f32_32x32x16_bf16(kf[c], qf[c], st, 0, 0, 0);

        // ---- per-lane softmax (scores already in log2 units)
        float tm = st[0];
#pragma unroll
        for (int i = 1; i < 16; ++i) tm = fmaxf(tm, st[i]);
        tm = fmaxf(tm, __shfl_xor(tm, 32, 64));
        if (__any(tm > mrun + 8.0f)) {       // defer-max: rescale only on real growth
            float mn = fmaxf(mrun, tm);
            float fs = fexp2(mrun - mn);
            mrun = mn;
            lrun *= fs;
#pragma unroll
            for (int ct = 0; ct < 4; ++ct)
#pragma unroll
                for (int i = 0; i < 16; ++i) o4[ct][i] *= fs;
        }
        float p[16];
        float sum = 0.f;
#pragma unroll
        for (int i = 0; i < 16; ++i) { p[i] = fexp2(st[i] - mrun); sum += p[i]; }
        sum += __shfl_xor(sum, 32, 64);
        lrun += sum;

        // ---- P -> bf16 B-fragments in-register (no LDS)
        short8 bp[2];
#pragma unroll
        for (int ch = 0; ch < 2; ++ch) {
            unsigned int wa = cvt_pk_bf16(p[ch * 8 + 0], p[ch * 8 + 1]);
            unsigned int wb = cvt_pk_bf16(p[ch * 8 + 2], p[ch * 8 + 3]);
            unsigned int wc = cvt_pk_bf16(p[ch * 8 + 4], p[ch * 8 + 5]);
            unsigned int wd = cvt_pk_bf16(p[ch * 8 + 6], p[ch * 8 + 7]);
            unsigned int xa = (unsigned int)__shfl_xor((int)wa, 32, 64);
            unsigned int xb = (unsigned int)__shfl_xor((int)wb, 32, 64);
            unsigned int xc = (unsigned int)__shfl_xor((int)wc, 32, 64);
            unsigned int xd = (unsigned int)__shfl_xor((int)wd, 32, 64);
            int4 w;
            w.x = (int)(hi ? xc : wa);   // elements 0,1
            w.y = (int)(hi ? xd : wb);   // elements 2,3
            w.z = (int)(hi ? wc : xa);   // elements 4,5
            w.w = (int)(hi ? wd : xb);   // elements 6,7
            bp[ch] = *(short8*)&w;
        }

        // ---- PV: O^T[d][q] += V^T x P^T
#pragma unroll
        for (int ct = 0; ct < 4; ++ct) {
            o4[ct] = __builtin_amdgcn_mfma_f32_32x32x16_bf16(vf[ct][0], bp[0], o4[ct], 0, 0, 0);
            o4[ct] = __builtin_amdgcn_mfma_f32_32x32x16_bf16(vf[ct][1], bp[1], o4[ct], 0, 0, 0);
        }
    }

    // ---- cross-wave combine (8 partials over kv) ----
    if (lane < 32) {                         // hi==0 half; both halves agree on m/l
        m_lds[wv_][r31] = mrun;
        l_lds[wv_][r31] = lrun;
    }
    __syncthreads();
    if (t < 32) {
        float gm = -1.0e30f;
#pragma unroll
        for (int w = 0; w < 8; ++w) gm = fmaxf(gm, m_lds[w][t]);
        float gl = 0.f;
#pragma unroll
        for (int w = 0; w < 8; ++w)
            gl += l_lds[w][t] * fexp2(m_lds[w][t] - gm);
        gm_lds[t] = gm;
        gl_lds[t] = gl;
    }
    __syncthreads();

    const float sc = fexp2(mrun - gm_lds[r31]);
    float* slot = (wv_ & 1) ? oB : oA;
    const int rnd = wv_ >> 1;                 // 0..3
    for (int rr = 0; rr < 4; ++rr) {
        if (rnd == rr) {
            if (rr == 0) {
#pragma unroll
                for (int ct = 0; ct < 4; ++ct)
#pragma unroll
                    for (int i = 0; i < 16; ++i) {
                        int d = ct * 32 + (i & 3) + 8 * (i >> 2) + 4 * hi;
                        slot[d * 33 + r31] = o4[ct][i] * sc;
                    }
            } else {
#pragma unroll
                for (int ct = 0; ct < 4; ++ct)
#pragma unroll
                    for (int i = 0; i < 16; ++i) {
                        int d = ct * 32 + (i & 3) + 8 * (i >> 2) + 4 * hi;
                        slot[d * 33 + r31] += o4[ct][i] * sc;
                    }
            }
        }
        __syncthreads();
    }

    // ---- final: (oA+oB)/gl, transpose O^T -> out[q][d]
    {
        int qq = t & 31, d0 = (t >> 5) * 8;
        float inv = 1.0f / gl_lds[qq];
        float* dst = out + (size_t)(qbase + qq) * DK_ + d0;
        float4 v0, v1;
        v0.x = (oA[(d0 + 0) * 33 + qq] + oB[(d0 + 0) * 33 + qq]) * inv;
        v0.y = (oA[(d0 + 1) * 33 + qq] + oB[(d0 + 1) * 33 + qq]) * inv;
        v0.z = (oA[(d0 + 2) * 33 + qq] + oB[(d0 + 2) * 33 + qq]) * inv;
        v0.w = (oA[(d0 + 3) * 33 + qq] + oB[(d0 + 3) * 33 + qq]) * inv;
        v1.x = (oA[(d0 + 4) * 33 + qq] + oB[(d0 + 4) * 33 + qq]) * inv;
        v1.y = (oA[(d0 + 5) * 33 + qq] + oB[(d0 + 5) * 33 + qq]) * inv;
        v1.z = (oA[(d0 + 6) * 33 + qq] + oB[(d0 + 6) * 33 + qq]) * inv;
        v1.w = (oA[(d0 + 7) * 33 + qq] + oB[(d0 + 7) * 33 + qq]) * inv;
        *(float4*)(dst)     = v0;
        *(float4*)(dst + 4) = v1;
    }
}

// ---------------------------------------------------------------------------
extern "C" void kernel_launch(void* const* d_in, const int* in_sizes, int n_in,
                              void* d_out, int out_size, void* d_ws, size_t ws_size,
                              hipStream_t stream) {
    const float* q  = (const float*)d_in[0];
    const float* k  = (const float*)d_in[1];
    const float* v  = (const float*)d_in[2];
    const float* wq = (const float*)d_in[3];
    const float* wk = (const float*)d_in[4];
    const float* wv = (const float*)d_in[5];
    float* out = (float*)d_out;

    char* ws = (char*)d_ws;
    u16* WT  = (u16*)ws;                                   // 786432 B
    u16* qp  = (u16*)(ws + 786432);                        // 4 MB
    u16* kp  = (u16*)(ws + 786432 + 4194304);              // 4 MB
    u16* vpT = (u16*)(ws + 786432 + 2 * 4194304);          // 4 MB

    prep_wt<<<dim3(1536), dim3(256), 0, stream>>>(wq, wk, wv, WT);
    proj<<<dim3(256, 3), dim3(256), 0, stream>>>(q, k, v, WT, qp, kp, vpT);
    attn<<<dim3(512), dim3(512), 0, stream>>>(qp, kp, vpT, out);
}